// Round 7
// baseline (720.926 us; speedup 1.0000x reference)
//
#include <hip/hip_runtime.h>
#include <cstdint>
#include <cstddef>

// Problem shape (fixed by the reference): B=8, C=192, Tx=512, Ty=2048.
#define BB 8
#define CC 192
#define TXX 512
#define TYY 2048
#define NG_MAX (TYY / 8)   // 256 groups of 8 rows

#define NEG_INF (-1e9f)
#define HALF_LOG_2PI 0.9189385332046727f  // 0.5*log(2*pi)

// ---- output layout (floats, concatenated in return order) ----
#define O1 8388608
#define O2 11534336
#define O3 14680064
#define O4 14680065

// ---- workspace layout (bytes) ----
#define WS_NEG   0           // neg_cent fp32 [B,Ty,Tx]           33,554,432 B
#define WS_S     33554432    // s_p_sq_r [B,C,Tx]                  3,145,728 B
#define WS_MSR   36700160    // m_p * s  [B,C,Tx]                  3,145,728 B
#define WS_BIAS  39845888    // nc1+nc4  [B,Tx]                       16,384 B
#define WS_DIRS  39862272    // dir bits [B,Ty/4,64] dwords        1,048,576 B
#define WS_IDX   40910848    // idx_map  [B,Ty] int                   65,536 B
#define WS_LENS  40976384    // int text_len[8], spec_len[8]             64 B
#define WS_PART  40976448    // kl partials [3072] float              12,288 B

typedef float f32x4 __attribute__((ext_vector_type(4)));

// ---------------------------------------------------------------------------
__global__ void k_zero(float* __restrict__ out) {
    int64_t i = (int64_t)blockIdx.x * blockDim.x + threadIdx.x;
    const int64_t n4 = (int64_t)BB * TYY * TXX / 4;
    float4 z4 = make_float4(0.f, 0.f, 0.f, 0.f);
    float4* p4 = (float4*)out;
    for (int64_t k = i; k < n4; k += (int64_t)gridDim.x * blockDim.x) p4[k] = z4;
    if (i < BB * TXX) out[O4 + i] = 0.0f;
}

__global__ void k_prep(const float* __restrict__ logs_p, const float* __restrict__ m_p,
                       float* __restrict__ s, float* __restrict__ msr) {
    int i = blockIdx.x * blockDim.x + threadIdx.x;
    float lp = logs_p[i], m = m_p[i];
    float sv = expf(-2.0f * lp);
    s[i] = sv;
    msr[i] = m * sv;
}

// 64 blocks x 64 threads -> 64 CUs active.
__global__ void k_bias(const float* __restrict__ logs_p, const float* __restrict__ m_p,
                       const float* __restrict__ msr, float* __restrict__ bias) {
    int i = blockIdx.x * blockDim.x + threadIdx.x;  // B*Tx = 4096 threads
    int b = i >> 9, x = i & (TXX - 1);
    size_t base = (size_t)b * CC * TXX + x;
    const float* lpb = logs_p + base;
    const float* mb  = m_p + base;
    const float* msb = msr + base;
    float acc = 0.f;
#pragma unroll 8
    for (int c = 0; c < CC; ++c)
        acc += -HALF_LOG_2PI - lpb[(size_t)c * TXX] - 0.5f * mb[(size_t)c * TXX] * msb[(size_t)c * TXX];
    bias[i] = acc;
}

__global__ void k_len(const float* __restrict__ tmask, const float* __restrict__ smask,
                      int* __restrict__ lens) {
    __shared__ float red[256];
    int b = blockIdx.x, tid = threadIdx.x;
    float ts = 0.f;
    for (int i = tid; i < TXX; i += 256) ts += tmask[b * TXX + i];
    red[tid] = ts; __syncthreads();
    for (int s = 128; s > 0; s >>= 1) { if (tid < s) red[tid] += red[tid + s]; __syncthreads(); }
    if (tid == 0) lens[b] = (int)(red[0] + 0.5f);
    __syncthreads();
    float ss = 0.f;
    for (int i = tid; i < TYY; i += 256) ss += smask[b * TYY + i];
    red[tid] = ss; __syncthreads();
    for (int s = 128; s > 0; s >>= 1) { if (tid < s) red[tid] += red[tid + s]; __syncthreads(); }
    if (tid == 0) lens[8 + b] = (int)(red[0] + 0.5f);
}

// neg_cent GEMM (R11 v1 tile: 64x64, BK=16, 8 blocks/CU).
// Masked tiles exit early (block-uniform). Poison in masked region is
// harmless to the DP/backtrack (see R14 note).
__global__ __launch_bounds__(256) void k_gemm(const float* __restrict__ z,
                                              const float* __restrict__ msr,
                                              const float* __restrict__ sarr,
                                              const float* __restrict__ bias,
                                              const int* __restrict__ lens,
                                              float* __restrict__ neg) {
    int x0 = blockIdx.x * 64, t0 = blockIdx.y * 64, b = blockIdx.z;
    if (x0 >= lens[b] || t0 >= lens[8 + b]) return;   // masked tile

    __shared__ float Zs[16][68], Ms[16][68], Ss[16][68];  // +4 pad
    int tid = threadIdx.x;
    int tx = tid & 15, ty = tid >> 4;
    const float* zb = z    + (size_t)b * CC * TYY;
    const float* mb = msr  + (size_t)b * CC * TXX;
    const float* sb = sarr + (size_t)b * CC * TXX;
    int lr = tid >> 4, lc = (tid & 15) * 4;
    float acc[4][4] = {};
    for (int k0 = 0; k0 < CC; k0 += 16) {
        float4 zv = *(const float4*)(zb + (size_t)(k0 + lr) * TYY + t0 + lc);
        float4 mv = *(const float4*)(mb + (size_t)(k0 + lr) * TXX + x0 + lc);
        float4 sv = *(const float4*)(sb + (size_t)(k0 + lr) * TXX + x0 + lc);
        __syncthreads();
        *(float4*)&Zs[lr][lc] = zv;
        *(float4*)&Ms[lr][lc] = mv;
        *(float4*)&Ss[lr][lc] = sv;
        __syncthreads();
#pragma unroll
        for (int k = 0; k < 16; ++k) {
            float4 a4  = *(const float4*)&Zs[k][ty * 4];
            float4 bm4 = *(const float4*)&Ms[k][tx * 4];
            float4 bs4 = *(const float4*)&Ss[k][tx * 4];
            float av[4]  = {a4.x, a4.y, a4.z, a4.w};
            float bmv[4] = {bm4.x, bm4.y, bm4.z, bm4.w};
            float bsv[4] = {bs4.x, bs4.y, bs4.z, bs4.w};
#pragma unroll
            for (int i2 = 0; i2 < 4; ++i2) {
                float a2 = -0.5f * av[i2] * av[i2];
#pragma unroll
                for (int j = 0; j < 4; ++j)
                    acc[i2][j] += av[i2] * bmv[j] + a2 * bsv[j];
            }
        }
    }
    float4 b4 = *(const float4*)(bias + b * TXX + x0 + tx * 4);
    float bv[4] = {b4.x, b4.y, b4.z, b4.w};
#pragma unroll
    for (int i2 = 0; i2 < 4; ++i2) {
        int t = t0 + ty * 4 + i2;
        float4 o;
        o.x = acc[i2][0] + bv[0]; o.y = acc[i2][1] + bv[1];
        o.z = acc[i2][2] + bv[2]; o.w = acc[i2][3] + bv[3];
        *(float4*)(neg + ((size_t)b * TYY + t) * TXX + x0 + tx * 4) = o;
    }
}

// ---------------------------------------------------------------------------
// MAS forward v10 (R21): TWO DP waves (x-split 256/256), 1-group skew,
// 5-slot LDS ring staged per-wave via global_load_lds. Backtrack fused.
//
// R20 post-mortem: VGPR stuck at 132 for the 3rd time -> regalloc/scheduler
// defeats cross-iteration register tiles; and with ONE wave the issue floor
// (~730 instr/group, VALU 2cy each) is ~1500cy/group vs 2456 measured.
// The x-axis is data-parallel (row op = elementwise + shift; only y is
// serial), so split x across 2 waves (issue parallelism) instead of
// fighting single-wave latency:
//   - wave A: x 0..255 (4 cols/lane); wave B: x 256..511, one group behind.
//     B's left boundary = A's v[3]@lane63 of row y-1, via bnd[32] LDS ring
//     (v3-proven; write range (8i..8i+7)&31 vs read range (8g-9..8g-2)&31
//     disjoint at 1-group skew).
//   - each wave stages ITS half-row (8 glds/group) into a 5-SLOT ring:
//     stage slot (i+3)%5 never touches B's read slot (i-1)%5; slot reuse
//     is 2 iterations after B's read, and lgkmcnt(0) runs before every
//     barrier -> no read/overwrite race.
//   - per-wave counted vmcnt ladder (8 loads + 2 dirs stores /group):
//     i=0:24, i=1:26, steady:28, tails 20/12/4 (exact induction in-line).
//   - lane->16B contiguous LDS reads: canonical conflict-free, swizzle
//     machinery DELETED.
//   - dirs bits: v3-proven (d<<4)|dl DPP merge, odd lanes store words
//     woff+(lane>>1) -> layout bit-identical, backtrack unchanged.
//   - one lgkmcnt(0)+s_barrier per group (2 waves, same CU).
// ---------------------------------------------------------------------------
#define WAIT_VM(N) do {                                                   \
    asm volatile("s_waitcnt vmcnt(" #N ")" ::: "memory");                 \
    __builtin_amdgcn_sched_barrier(0);                                    \
} while (0)

#define BARRIER() do {                                                    \
    asm volatile("s_waitcnt lgkmcnt(0)" ::: "memory");                    \
    __builtin_amdgcn_sched_barrier(0);                                    \
    __builtin_amdgcn_s_barrier();                                         \
    __builtin_amdgcn_sched_barrier(0);                                    \
} while (0)

#define GLDS(GP, LP)                                                      \
    __builtin_amdgcn_global_load_lds(                                     \
        (__attribute__((address_space(1))) void*)(GP),                    \
        (__attribute__((address_space(3))) void*)(LP), 16, 0, 0)

// Stage own half of group G (8 rows x 1KB) into ring slot S.
#define STAGE(G, S) do {                                                  \
    const char* gb_ = gbase + (size_t)(G) * 16384 + xhalf + lane * 16;    \
    char* lb_ = ring + (S) * 16384 + xhalf;                               \
    _Pragma("unroll")                                                     \
    for (int r_ = 0; r_ < 8; ++r_)                                        \
        GLDS(gb_ + r_ * 2048, lb_ + r_ * 2048);                          \
} while (0)

// One DP row (y>0). 4 cols/lane. pl: lane l gets lane l-1's v[3] (DPP shr1,
// old=NEG_INF covers lane0-A); lane0-B overridden with bn value.
#define DPR4(Q, R, YB) do {                                                   \
    unsigned d_ = 0;                                                          \
    float pl_ = __int_as_float(__builtin_amdgcn_update_dpp(                   \
        ninf_i, __float_as_int(v[3]), 0x138, 0xF, 0xF, false));               \
    if (useBn && lane == 0) pl_ = bnv[R];                                     \
    float n0_ = Q[0] + fmaxf(v[0], pl_);  if (pl_  > v[0]) d_ |= 1u;          \
    float n1_ = Q[1] + fmaxf(v[1], v[0]); if (v[0] > v[1]) d_ |= 2u;          \
    float n2_ = Q[2] + fmaxf(v[2], v[1]); if (v[1] > v[2]) d_ |= 4u;          \
    float n3_ = Q[3] + fmaxf(v[3], v[2]); if (v[2] > v[3]) d_ |= 8u;          \
    v[0] = n0_; v[1] = n1_; v[2] = n2_; v[3] = n3_;                           \
    unsigned t_ = (unsigned)((YB) + (R) - xb4);                               \
    if (t_ < 4u) d_ |= 1u << t_;          /* fold x==y */                     \
    unsigned dl_ = (unsigned)__builtin_amdgcn_update_dpp(                     \
        0, (int)d_, 0x138, 0xF, 0xF, false);                                  \
    acc |= ((d_ << 4) | dl_) << (((R) & 3) * 8);                              \
    if (isA && lane == 63) bnd[((YB) + (R)) & 31] = v[3];                     \
} while (0)

// Row y==0: only x==0 scored; no DP; x==y fold hits lane0-A only.
#define DPR0(Q) do {                                                          \
    if (isA && lane == 0) v[0] = Q[0];                                        \
    unsigned d_ = (isA && lane == 0) ? 1u : 0u;                               \
    unsigned dl_ = (unsigned)__builtin_amdgcn_update_dpp(                     \
        0, (int)d_, 0x138, 0xF, 0xF, false);                                  \
    acc |= (d_ << 4) | dl_;                                                   \
    if (isA && lane == 63) bnd[0] = v[3];                                     \
} while (0)

__global__ __launch_bounds__(128, 1) void k_fwd(const float* __restrict__ neg,
                                                const int* __restrict__ lens,
                                                uint32_t* __restrict__ dirs,
                                                int* __restrict__ idx_map) {
    __shared__ __align__(16) char ring[5 * 16384];   // 80 KiB, 5 slots
    __shared__ float bnd[32];                        // A->B boundary ring
    int b = blockIdx.x, tid = threadIdx.x;
    int wave = tid >> 6, lane = tid & 63;
    bool isA = (wave == 0);
    bool useBn = !isA;
    int xhalf = isA ? 0 : 1024;          // byte offset of own half-row
    int xbase = isA ? 0 : 256;
    int xb4 = xbase + 4 * lane;
    int woff = isA ? 0 : 32;
    const char* gbase = (const char*)(neg + (size_t)b * TYY * TXX);
    uint32_t* db32 = dirs + (size_t)b * (TYY / 4) * 64;
    int slen = lens[8 + b];
    int ng = (slen + 7) >> 3;    // 192..256 (slen >= 1536)
    int ninf_i = __float_as_int(NEG_INF);

    float v[4];
#pragma unroll
    for (int j = 0; j < 4; ++j) v[j] = NEG_INF;
    unsigned acc = 0;

    STAGE(0, 0); STAGE(1, 1); STAGE(2, 2);
    int sS = 3, sA = 0, sB = 4;

#pragma unroll 1
    for (int i = 0; i <= ng; ++i) {
        BARRIER();                       // bnd iter i-1 visible; ds drained
        if (i + 3 < ng) STAGE(i + 3, sS);
        if (i == 0)            { WAIT_VM(24); }
        else if (i == 1)       { WAIT_VM(26); }
        else if (i + 3 < ng)   { WAIT_VM(28); }
        else if (i + 2 < ng)   { WAIT_VM(20); }
        else if (i + 1 < ng)   { WAIT_VM(12); }
        else                   { WAIT_VM(4);  }
        int g = isA ? i : i - 1;
        if ((unsigned)g < (unsigned)ng) {
            int sR = isA ? sA : sB;
            const char* sp_ = ring + sR * 16384 + xhalf + lane * 16;
            f32x4 q0 = *(const f32x4*)(sp_);
            f32x4 q1 = *(const f32x4*)(sp_ + 2048);
            f32x4 q2 = *(const f32x4*)(sp_ + 4096);
            f32x4 q3 = *(const f32x4*)(sp_ + 6144);
            f32x4 q4 = *(const f32x4*)(sp_ + 8192);
            f32x4 q5 = *(const f32x4*)(sp_ + 10240);
            f32x4 q6 = *(const f32x4*)(sp_ + 12288);
            f32x4 q7 = *(const f32x4*)(sp_ + 14336);
            float bnv[8];
            if (useBn) {
                int bb_ = 8 * g - 1;
#pragma unroll
                for (int k = 0; k < 8; ++k) bnv[k] = bnd[(bb_ + k) & 31];
            }
            __builtin_amdgcn_sched_barrier(0);
            uint32_t* dp_ = db32 + ((unsigned)g << 7) + woff + (lane >> 1);
            int yb = 8 * g;
            if (yb == 0) {
                DPR0(q0);
                DPR4(q1, 1, yb); DPR4(q2, 2, yb); DPR4(q3, 3, yb);
            } else {
                DPR4(q0, 0, yb); DPR4(q1, 1, yb);
                DPR4(q2, 2, yb); DPR4(q3, 3, yb);
            }
            if (lane & 1) dp_[0] = acc;
            acc = 0;
            DPR4(q4, 4, yb); DPR4(q5, 5, yb);
            DPR4(q6, 6, yb); DPR4(q7, 7, yb);
            if (lane & 1) dp_[64] = acc;
            acc = 0;
        }
        if (++sS == 5) sS = 0;
        if (++sA == 5) sA = 0;
        if (++sB == 5) sB = 0;
    }

    // ---- fused backtrack (wave A only; all dirs stores drained first) ----
    WAIT_VM(0);
    BARRIER();
    if (!isA) return;
    {
        int tlen = lens[b];
        int idx = tlen - 1;
        int y0 = slen - 1;
        while (y0 >= 0) {
            int nsteps = (y0 + 1 < 32) ? y0 + 1 : 32;
            int y = y0 - lane;
            int yy = (y < 0) ? 0 : y;
            int w0 = (idx >> 5) - 1;
            if (w0 < 0) w0 = 0;
            if (w0 > 14) w0 = 14;
            int qrow = (yy >> 2) * 64;
            int byteoff = (yy & 3) * 8;
            uint32_t lo = 0, hi = 0;
            if (lane < 32) {
#pragma unroll
                for (int k = 0; k < 4; ++k)
                    lo |= ((db32[qrow + 4 * w0 + k] >> byteoff) & 0xffu) << (8 * k);
#pragma unroll
                for (int k = 0; k < 4; ++k)
                    hi |= ((db32[qrow + 4 * w0 + 4 + k] >> byteoff) & 0xffu) << (8 * k);
            }
            int base = w0 << 5;
            int cap = 0;
#pragma unroll
            for (int j = 0; j < 32; ++j) {
                if (lane == j) cap = idx;
                uint32_t l = (uint32_t)__builtin_amdgcn_readlane((int)lo, j);
                uint32_t h = (uint32_t)__builtin_amdgcn_readlane((int)hi, j);
                int bp = idx - base;              // 0..63
                uint32_t word = (bp & 32) ? h : l;
                int bit = (int)((word >> (bp & 31)) & 1u);
                int move = (int)(idx != 0) & bit;
                idx -= move;
            }
            if (lane < nsteps) idx_map[b * TYY + (y0 - lane)] = cap;
            y0 -= 32;
        }
    }
}

// Scatter path one-hots + duration histogram from idx_map.
__global__ void k_scatter(const int* __restrict__ lens, const int* __restrict__ idx_map,
                          float* __restrict__ out) {
    int i = blockIdx.x * blockDim.x + threadIdx.x;  // B*Ty threads
    int b = i >> 11, y = i & (TYY - 1);
    if (y < lens[8 + b]) {
        int x = idx_map[i];
        out[(size_t)i * TXX + x] = 1.0f;
        atomicAdd(&out[O4 + b * TXX + x], 1.0f);
    }
}

// Gather m_p/logs_p onto spec frames via idx_map; fused KL partial sums.
__global__ __launch_bounds__(256) void k_gather(const float* __restrict__ z_p,
                                                const float* __restrict__ m_p,
                                                const float* __restrict__ logs_p,
                                                const float* __restrict__ logs_q,
                                                const int* __restrict__ lens,
                                                const int* __restrict__ idx_map,
                                                float* __restrict__ out,
                                                float* __restrict__ partials) {
    const int S = BB * CC * TYY / 4;
    int base = blockIdx.x * 256 + threadIdx.x;
    float klsum = 0.f;
#pragma unroll
    for (int r = 0; r < 4; ++r) {
        int i = base + r * S;
        int t = i & (TYY - 1);
        int bc = i >> 11;
        int b = bc / CC;
        float ma = 0.f, la = 0.f;
        if (t < lens[8 + b]) {
            int x = idx_map[b * TYY + t];
            size_t off = (size_t)bc * TXX + x;
            ma = m_p[off];
            la = logs_p[off];
            float zv = z_p[i], lq = logs_q[i];
            float dz = zv - ma;
            klsum += la - lq - 0.5f + 0.5f * dz * dz * expf(-2.0f * la);
        }
        out[O1 + i] = ma;
        out[O2 + i] = la;
    }
    for (int o = 32; o > 0; o >>= 1) klsum += __shfl_down(klsum, o);
    __shared__ float red[4];
    if ((threadIdx.x & 63) == 0) red[threadIdx.x >> 6] = klsum;
    __syncthreads();
    if (threadIdx.x == 0) partials[blockIdx.x] = red[0] + red[1] + red[2] + red[3];
}

__global__ void k_final(const float* __restrict__ partials, const int* __restrict__ lens,
                        float* __restrict__ out) {
    float s = 0.f;
    for (int i = threadIdx.x; i < 3072; i += 256) s += partials[i];
    for (int o = 32; o > 0; o >>= 1) s += __shfl_down(s, o);
    __shared__ float red[4];
    if ((threadIdx.x & 63) == 0) red[threadIdx.x >> 6] = s;
    __syncthreads();
    if (threadIdx.x == 0) {
        float tot = 0.f;
        for (int b = 0; b < 8; ++b) tot += (float)lens[8 + b];
        out[O3] = (red[0] + red[1] + red[2] + red[3]) / tot;
    }
}

extern "C" void kernel_launch(void* const* d_in, const int* in_sizes, int n_in,
                              void* d_out, int out_size, void* d_ws, size_t ws_size,
                              hipStream_t stream) {
    const float* z_p    = (const float*)d_in[0];
    const float* m_p    = (const float*)d_in[1];
    const float* logs_p = (const float*)d_in[2];
    const float* logs_q = (const float*)d_in[3];
    const float* tmask  = (const float*)d_in[4];
    const float* smask  = (const float*)d_in[5];
    float* out = (float*)d_out;
    char* ws = (char*)d_ws;

    float*    neg      = (float*)(ws + WS_NEG);
    float*    sarr     = (float*)(ws + WS_S);
    float*    msr      = (float*)(ws + WS_MSR);
    float*    bias     = (float*)(ws + WS_BIAS);
    uint32_t* dirs     = (uint32_t*)(ws + WS_DIRS);
    int*      idx_map  = (int*)(ws + WS_IDX);
    int*      lens     = (int*)(ws + WS_LENS);
    float*    partials = (float*)(ws + WS_PART);

    hipLaunchKernelGGL(k_zero,    dim3(2048),      dim3(256), 0, stream, out);
    hipLaunchKernelGGL(k_prep,    dim3(3072),      dim3(256), 0, stream, logs_p, m_p, sarr, msr);
    hipLaunchKernelGGL(k_bias,    dim3(64),        dim3(64),  0, stream, logs_p, m_p, msr, bias);
    hipLaunchKernelGGL(k_len,     dim3(8),         dim3(256), 0, stream, tmask, smask, lens);
    hipLaunchKernelGGL(k_gemm,    dim3(8, 32, 8),  dim3(256), 0, stream, z_p, msr, sarr, bias, lens, neg);
    hipLaunchKernelGGL(k_fwd,     dim3(8),         dim3(128), 0, stream, neg, lens, dirs, idx_map);
    hipLaunchKernelGGL(k_scatter, dim3(64),        dim3(256), 0, stream, lens, idx_map, out);
    hipLaunchKernelGGL(k_gather,  dim3(3072),      dim3(256), 0, stream, z_p, m_p, logs_p, logs_q,
                       lens, idx_map, out, partials);
    hipLaunchKernelGGL(k_final,   dim3(1),         dim3(256), 0, stream, partials, lens, out);
}

// Round 9
// 586.059 us; speedup vs baseline: 1.2301x; 1.2301x over previous
//
#include <hip/hip_runtime.h>
#include <cstdint>
#include <cstddef>

// Problem shape (fixed by the reference): B=8, C=192, Tx=512, Ty=2048.
#define BB 8
#define CC 192
#define TXX 512
#define TYY 2048

#define NEG_INF (-1e9f)
#define HALF_LOG_2PI 0.9189385332046727f  // 0.5*log(2*pi)

// ---- output layout (floats, concatenated in return order) ----
#define O1 8388608
#define O2 11534336
#define O3 14680064
#define O4 14680065

// ---- workspace layout (bytes) ----
#define WS_NEG   0           // neg_cent fp32 [B,Ty,Tx]           33,554,432 B
#define WS_S     33554432    // s_p_sq_r [B,C,Tx]                  3,145,728 B
#define WS_MSR   36700160    // m_p * s  [B,C,Tx]                  3,145,728 B
#define WS_BIAS  39845888    // nc1+nc4  [B,Tx]                       16,384 B
#define WS_DIRS  39862272    // dir bits [B,Ty/4,64] dwords        1,048,576 B
#define WS_IDX   40910848    // idx_map  [B,Ty] int                   65,536 B
#define WS_LENS  40976384    // int text_len[8], spec_len[8]             64 B
#define WS_PART  40976448    // kl partials [3072] float              12,288 B

typedef float f32x4 __attribute__((ext_vector_type(4)));

// ---------------------------------------------------------------------------
__global__ void k_zero(float* __restrict__ out) {
    int64_t i = (int64_t)blockIdx.x * blockDim.x + threadIdx.x;
    const int64_t n4 = (int64_t)BB * TYY * TXX / 4;
    float4 z4 = make_float4(0.f, 0.f, 0.f, 0.f);
    float4* p4 = (float4*)out;
    for (int64_t k = i; k < n4; k += (int64_t)gridDim.x * blockDim.x) p4[k] = z4;
    if (i < BB * TXX) out[O4 + i] = 0.0f;
}

__global__ void k_prep(const float* __restrict__ logs_p, const float* __restrict__ m_p,
                       float* __restrict__ s, float* __restrict__ msr) {
    int i = blockIdx.x * blockDim.x + threadIdx.x;
    float lp = logs_p[i], m = m_p[i];
    float sv = expf(-2.0f * lp);
    s[i] = sv;
    msr[i] = m * sv;
}

// 64 blocks x 64 threads -> 64 CUs active.
__global__ void k_bias(const float* __restrict__ logs_p, const float* __restrict__ m_p,
                       const float* __restrict__ msr, float* __restrict__ bias) {
    int i = blockIdx.x * blockDim.x + threadIdx.x;  // B*Tx = 4096 threads
    int b = i >> 9, x = i & (TXX - 1);
    size_t base = (size_t)b * CC * TXX + x;
    const float* lpb = logs_p + base;
    const float* mb  = m_p + base;
    const float* msb = msr + base;
    float acc = 0.f;
#pragma unroll 8
    for (int c = 0; c < CC; ++c)
        acc += -HALF_LOG_2PI - lpb[(size_t)c * TXX] - 0.5f * mb[(size_t)c * TXX] * msb[(size_t)c * TXX];
    bias[i] = acc;
}

__global__ void k_len(const float* __restrict__ tmask, const float* __restrict__ smask,
                      int* __restrict__ lens) {
    __shared__ float red[256];
    int b = blockIdx.x, tid = threadIdx.x;
    float ts = 0.f;
    for (int i = tid; i < TXX; i += 256) ts += tmask[b * TXX + i];
    red[tid] = ts; __syncthreads();
    for (int s = 128; s > 0; s >>= 1) { if (tid < s) red[tid] += red[tid + s]; __syncthreads(); }
    if (tid == 0) lens[b] = (int)(red[0] + 0.5f);
    __syncthreads();
    float ss = 0.f;
    for (int i = tid; i < TYY; i += 256) ss += smask[b * TYY + i];
    red[tid] = ss; __syncthreads();
    for (int s = 128; s > 0; s >>= 1) { if (tid < s) red[tid] += red[tid + s]; __syncthreads(); }
    if (tid == 0) lens[8 + b] = (int)(red[0] + 0.5f);
}

// neg_cent GEMM (R11 v1 tile: 64x64, BK=16, 8 blocks/CU).
// Masked tiles exit early (block-uniform). Poison in masked region is
// harmless to the DP/backtrack (see R14 note).
__global__ __launch_bounds__(256) void k_gemm(const float* __restrict__ z,
                                              const float* __restrict__ msr,
                                              const float* __restrict__ sarr,
                                              const float* __restrict__ bias,
                                              const int* __restrict__ lens,
                                              float* __restrict__ neg) {
    int x0 = blockIdx.x * 64, t0 = blockIdx.y * 64, b = blockIdx.z;
    if (x0 >= lens[b] || t0 >= lens[8 + b]) return;   // masked tile

    __shared__ float Zs[16][68], Ms[16][68], Ss[16][68];  // +4 pad
    int tid = threadIdx.x;
    int tx = tid & 15, ty = tid >> 4;
    const float* zb = z    + (size_t)b * CC * TYY;
    const float* mb = msr  + (size_t)b * CC * TXX;
    const float* sb = sarr + (size_t)b * CC * TXX;
    int lr = tid >> 4, lc = (tid & 15) * 4;
    float acc[4][4] = {};
    for (int k0 = 0; k0 < CC; k0 += 16) {
        float4 zv = *(const float4*)(zb + (size_t)(k0 + lr) * TYY + t0 + lc);
        float4 mv = *(const float4*)(mb + (size_t)(k0 + lr) * TXX + x0 + lc);
        float4 sv = *(const float4*)(sb + (size_t)(k0 + lr) * TXX + x0 + lc);
        __syncthreads();
        *(float4*)&Zs[lr][lc] = zv;
        *(float4*)&Ms[lr][lc] = mv;
        *(float4*)&Ss[lr][lc] = sv;
        __syncthreads();
#pragma unroll
        for (int k = 0; k < 16; ++k) {
            float4 a4  = *(const float4*)&Zs[k][ty * 4];
            float4 bm4 = *(const float4*)&Ms[k][tx * 4];
            float4 bs4 = *(const float4*)&Ss[k][tx * 4];
            float av[4]  = {a4.x, a4.y, a4.z, a4.w};
            float bmv[4] = {bm4.x, bm4.y, bm4.z, bm4.w};
            float bsv[4] = {bs4.x, bs4.y, bs4.z, bs4.w};
#pragma unroll
            for (int i2 = 0; i2 < 4; ++i2) {
                float a2 = -0.5f * av[i2] * av[i2];
#pragma unroll
                for (int j = 0; j < 4; ++j)
                    acc[i2][j] += av[i2] * bmv[j] + a2 * bsv[j];
            }
        }
    }
    float4 b4 = *(const float4*)(bias + b * TXX + x0 + tx * 4);
    float bv[4] = {b4.x, b4.y, b4.z, b4.w};
#pragma unroll
    for (int i2 = 0; i2 < 4; ++i2) {
        int t = t0 + ty * 4 + i2;
        float4 o;
        o.x = acc[i2][0] + bv[0]; o.y = acc[i2][1] + bv[1];
        o.z = acc[i2][2] + bv[2]; o.w = acc[i2][3] + bv[3];
        *(float4*)(neg + ((size_t)b * TYY + t) * TXX + x0 + tx * 4) = o;
    }
}

// ---------------------------------------------------------------------------
// MAS forward v11 (R22/R23 rerun): v5 (best measured, 203us) with the SPILL
// removed. (R23: previous bench attempt died to container infra, not the
// kernel; source unchanged.)
//
// Evidence v4-v10: single-wave asm-pinned VGPR prefetch (v5) beats every
// LDS-ring / multi-wave variant. But v5's 3x 8-row buffers need 192 VGPRs
// and VGPR_Count read 116 -> the allocator spilled buffer slices to
// scratch; the pipeline still partially worked, 203us. v11 keeps the exact
// v5 mechanism (GLOAD4 64-bit-VGPR-pointer asm loads; DPROW byte-for-byte;
// dirs layout unchanged) and shrinks the granule: 4-ROW groups x 4 buffers
// = 128 VGPRs of buffer + ~35 misc -> fits, no spill. Prefetch distance 3
// groups = 12 rows (~1250cy lead vs ~500cy L3-ish latency; FETCH shows
// only ~14.7MB of the 33.5MB comes from HBM).
//
// vmcnt ladder (8 loads + 1 dirs store per group; iter g issues L_{g+3}
// then 1 store at the end): at iter-g wait, ops newer than L_g:
//   steady g>=3: S(g-3)+L(g+1)+S(g-2)+L(g+2)+S(g-1)+L(g+3) = 27
//   g<3 (no older stores yet): >=24 -> use 24 (stricter, safe)
//   tail g+3>=ng4,g+2<ng4: 1+8+1+8+1 = 19
//   tail g+2>=ng4,g+1<ng4: S+L(g+1)+S+S = 11
//   last: 3 stores newer = 3
// Backtrack fused after WAIT_VM(0) (one launch saved; dirs L2-hot).
// ---------------------------------------------------------------------------
#define GLOAD4(DST, PTR, OFF)                                             \
    asm volatile("global_load_dwordx4 %0, %1, off offset:" #OFF           \
                 : "=v"(DST) : "v"(PTR) : "memory")

#define WAIT_VM(N) do {                                                   \
    asm volatile("s_waitcnt vmcnt(" #N ")" ::: "memory");                 \
    __builtin_amdgcn_sched_barrier(0);                                    \
} while (0)

// 4 rows x 512 floats; lane owns 32B (two float4) per row. 2 base pointers
// (rows {0,1},{2,3}), imm offsets {0,16,2048,2064} (13b signed, max 2064).
#define LOADG(DST, G) do {                                                \
    const char* p0_ = (const char*)nc4 + (size_t)(G) * 8192 + lane * 32;  \
    const char* p2_ = p0_ + 4096;                                         \
    GLOAD4(DST[0], p0_, 0);    GLOAD4(DST[1], p0_, 16);                   \
    GLOAD4(DST[2], p0_, 2048); GLOAD4(DST[3], p0_, 2064);                 \
    GLOAD4(DST[4], p2_, 0);    GLOAD4(DST[5], p2_, 16);                   \
    GLOAD4(DST[6], p2_, 2048); GLOAD4(DST[7], p2_, 2064);                 \
} while (0)

// One DP row (v5 byte-for-byte; y_ = 4*g + R here).
#define DPROW(CUR, YB, R) do {                                                \
    int y_ = (YB) + (R);                                                      \
    float s0_ = CUR[2*(R)][0],   s1_ = CUR[2*(R)][1];                         \
    float s2_ = CUR[2*(R)][2],   s3_ = CUR[2*(R)][3];                         \
    float s4_ = CUR[2*(R)+1][0], s5_ = CUR[2*(R)+1][1];                       \
    float s6_ = CUR[2*(R)+1][2], s7_ = CUR[2*(R)+1][3];                       \
    unsigned d_ = 0;                                                          \
    if (y_ == 0) {                                                            \
        if (lane == 0) v[0] = s0_;   /* only x==0 scored on row 0 */          \
    } else {                                                                  \
        float pl_ = __int_as_float(__builtin_amdgcn_update_dpp(               \
            0, __float_as_int(v[7]), 0x138, 0xF, 0xF, false));                \
        if (lane == 0) pl_ = NEG_INF;                                         \
        float n0_ = s0_ + fmaxf(v[0], pl_);  if (pl_  > v[0]) d_ |= 1u;       \
        float n1_ = s1_ + fmaxf(v[1], v[0]); if (v[0] > v[1]) d_ |= 2u;       \
        float n2_ = s2_ + fmaxf(v[2], v[1]); if (v[1] > v[2]) d_ |= 4u;       \
        float n3_ = s3_ + fmaxf(v[3], v[2]); if (v[2] > v[3]) d_ |= 8u;       \
        float n4_ = s4_ + fmaxf(v[4], v[3]); if (v[3] > v[4]) d_ |= 16u;      \
        float n5_ = s5_ + fmaxf(v[5], v[4]); if (v[4] > v[5]) d_ |= 32u;      \
        float n6_ = s6_ + fmaxf(v[6], v[5]); if (v[5] > v[6]) d_ |= 64u;      \
        float n7_ = s7_ + fmaxf(v[7], v[6]); if (v[6] > v[7]) d_ |= 128u;     \
        v[0] = n0_; v[1] = n1_; v[2] = n2_; v[3] = n3_;                       \
        v[4] = n4_; v[5] = n5_; v[6] = n6_; v[7] = n7_;                       \
    }                                                                         \
    unsigned t_ = (unsigned)(y_ - 8 * lane);                                  \
    if (t_ < 8u) d_ |= 1u << t_;          /* fold x==y for backtrack */       \
    acc |= d_ << (((R) & 3) * 8);                                             \
    if (((R) & 3) == 3) { db32[(y_ >> 2) * 64 + lane] = acc; acc = 0; }       \
} while (0)

#define FWD_ITER(G, CUR, NXT) do {                                \
    int g_ = (G);                                                 \
    if (g_ + 3 < ng4) {                                           \
        LOADG(NXT, g_ + 3);  /* prefetch 3 ahead */               \
        if (g_ >= 3) { WAIT_VM(27); } else { WAIT_VM(24); }       \
    } else if (g_ + 2 < ng4) {                                    \
        WAIT_VM(19);                                              \
    } else if (g_ + 1 < ng4) {                                    \
        WAIT_VM(11);                                              \
    } else {                                                      \
        WAIT_VM(3);                                               \
    }                                                             \
    int yb_ = 4 * g_;                                             \
    DPROW(CUR, yb_, 0); DPROW(CUR, yb_, 1);                       \
    DPROW(CUR, yb_, 2); DPROW(CUR, yb_, 3);                       \
} while (0)

__global__ __launch_bounds__(64, 1) void k_fwd(const float* __restrict__ neg,
                                               const int* __restrict__ lens,
                                               uint32_t* __restrict__ dirs,
                                               int* __restrict__ idx_map) {
    int b = blockIdx.x, lane = threadIdx.x;
    const float* nc4 = neg + (size_t)b * TYY * TXX;   // byte math in LOADG
    uint32_t* db32 = dirs + (size_t)b * (TYY / 4) * 64;
    int slen = lens[8 + b];
    int ng4 = (slen + 3) >> 2;   // 4-row groups: 384..512 (slen >= 1536)

    float v[8];
#pragma unroll
    for (int j = 0; j < 8; ++j) v[j] = NEG_INF;
    unsigned acc = 0;

    f32x4 bufA[8], bufB[8], bufC[8], bufD[8];  // 4 groups in flight (128 VGPR)
    LOADG(bufA, 0);
    LOADG(bufB, 1);
    LOADG(bufC, 2);

#pragma unroll 1
    for (int p = 0; p < ng4; p += 4) {
        FWD_ITER(p, bufA, bufD);
        if (p + 1 < ng4) FWD_ITER(p + 1, bufB, bufA);
        if (p + 2 < ng4) FWD_ITER(p + 2, bufC, bufB);
        if (p + 3 < ng4) FWD_ITER(p + 3, bufD, bufC);
    }

    // ---- fused backtrack (dirs stores drained first) ----
    WAIT_VM(0);
    {
        int tlen = lens[b];
        int idx = tlen - 1;
        int y0 = slen - 1;
        while (y0 >= 0) {
            int nsteps = (y0 + 1 < 32) ? y0 + 1 : 32;
            int y = y0 - lane;
            int yy = (y < 0) ? 0 : y;
            int w0 = (idx >> 5) - 1;
            if (w0 < 0) w0 = 0;
            if (w0 > 14) w0 = 14;
            int qrow = (yy >> 2) * 64;
            int byteoff = (yy & 3) * 8;
            uint32_t lo = 0, hi = 0;
            if (lane < 32) {
#pragma unroll
                for (int k = 0; k < 4; ++k)
                    lo |= ((db32[qrow + 4 * w0 + k] >> byteoff) & 0xffu) << (8 * k);
#pragma unroll
                for (int k = 0; k < 4; ++k)
                    hi |= ((db32[qrow + 4 * w0 + 4 + k] >> byteoff) & 0xffu) << (8 * k);
            }
            int base = w0 << 5;
            int cap = 0;
#pragma unroll
            for (int j = 0; j < 32; ++j) {
                if (lane == j) cap = idx;
                uint32_t l = (uint32_t)__builtin_amdgcn_readlane((int)lo, j);
                uint32_t h = (uint32_t)__builtin_amdgcn_readlane((int)hi, j);
                int bp = idx - base;              // 0..63
                uint32_t word = (bp & 32) ? h : l;
                int bit = (int)((word >> (bp & 31)) & 1u);
                int move = (int)(idx != 0) & bit;
                idx -= move;
            }
            if (lane < nsteps) idx_map[b * TYY + (y0 - lane)] = cap;
            y0 -= 32;
        }
    }
}

// Scatter path one-hots + duration histogram from idx_map.
__global__ void k_scatter(const int* __restrict__ lens, const int* __restrict__ idx_map,
                          float* __restrict__ out) {
    int i = blockIdx.x * blockDim.x + threadIdx.x;  // B*Ty threads
    int b = i >> 11, y = i & (TYY - 1);
    if (y < lens[8 + b]) {
        int x = idx_map[i];
        out[(size_t)i * TXX + x] = 1.0f;
        atomicAdd(&out[O4 + b * TXX + x], 1.0f);
    }
}

// Gather m_p/logs_p onto spec frames via idx_map; fused KL partial sums.
__global__ __launch_bounds__(256) void k_gather(const float* __restrict__ z_p,
                                                const float* __restrict__ m_p,
                                                const float* __restrict__ logs_p,
                                                const float* __restrict__ logs_q,
                                                const int* __restrict__ lens,
                                                const int* __restrict__ idx_map,
                                                float* __restrict__ out,
                                                float* __restrict__ partials) {
    const int S = BB * CC * TYY / 4;
    int base = blockIdx.x * 256 + threadIdx.x;
    float klsum = 0.f;
#pragma unroll
    for (int r = 0; r < 4; ++r) {
        int i = base + r * S;
        int t = i & (TYY - 1);
        int bc = i >> 11;
        int b = bc / CC;
        float ma = 0.f, la = 0.f;
        if (t < lens[8 + b]) {
            int x = idx_map[b * TYY + t];
            size_t off = (size_t)bc * TXX + x;
            ma = m_p[off];
            la = logs_p[off];
            float zv = z_p[i], lq = logs_q[i];
            float dz = zv - ma;
            klsum += la - lq - 0.5f + 0.5f * dz * dz * expf(-2.0f * la);
        }
        out[O1 + i] = ma;
        out[O2 + i] = la;
    }
    for (int o = 32; o > 0; o >>= 1) klsum += __shfl_down(klsum, o);
    __shared__ float red[4];
    if ((threadIdx.x & 63) == 0) red[threadIdx.x >> 6] = klsum;
    __syncthreads();
    if (threadIdx.x == 0) partials[blockIdx.x] = red[0] + red[1] + red[2] + red[3];
}

__global__ void k_final(const float* __restrict__ partials, const int* __restrict__ lens,
                        float* __restrict__ out) {
    float s = 0.f;
    for (int i = threadIdx.x; i < 3072; i += 256) s += partials[i];
    for (int o = 32; o > 0; o >>= 1) s += __shfl_down(s, o);
    __shared__ float red[4];
    if ((threadIdx.x & 63) == 0) red[threadIdx.x >> 6] = s;
    __syncthreads();
    if (threadIdx.x == 0) {
        float tot = 0.f;
        for (int b = 0; b < 8; ++b) tot += (float)lens[8 + b];
        out[O3] = (red[0] + red[1] + red[2] + red[3]) / tot;
    }
}

extern "C" void kernel_launch(void* const* d_in, const int* in_sizes, int n_in,
                              void* d_out, int out_size, void* d_ws, size_t ws_size,
                              hipStream_t stream) {
    const float* z_p    = (const float*)d_in[0];
    const float* m_p    = (const float*)d_in[1];
    const float* logs_p = (const float*)d_in[2];
    const float* logs_q = (const float*)d_in[3];
    const float* tmask  = (const float*)d_in[4];
    const float* smask  = (const float*)d_in[5];
    float* out = (float*)d_out;
    char* ws = (char*)d_ws;

    float*    neg      = (float*)(ws + WS_NEG);
    float*    sarr     = (float*)(ws + WS_S);
    float*    msr      = (float*)(ws + WS_MSR);
    float*    bias     = (float*)(ws + WS_BIAS);
    uint32_t* dirs     = (uint32_t*)(ws + WS_DIRS);
    int*      idx_map  = (int*)(ws + WS_IDX);
    int*      lens     = (int*)(ws + WS_LENS);
    float*    partials = (float*)(ws + WS_PART);

    hipLaunchKernelGGL(k_zero,    dim3(2048),      dim3(256), 0, stream, out);
    hipLaunchKernelGGL(k_prep,    dim3(3072),      dim3(256), 0, stream, logs_p, m_p, sarr, msr);
    hipLaunchKernelGGL(k_bias,    dim3(64),        dim3(64),  0, stream, logs_p, m_p, msr, bias);
    hipLaunchKernelGGL(k_len,     dim3(8),         dim3(256), 0, stream, tmask, smask, lens);
    hipLaunchKernelGGL(k_gemm,    dim3(8, 32, 8),  dim3(256), 0, stream, z_p, msr, sarr, bias, lens, neg);
    hipLaunchKernelGGL(k_fwd,     dim3(8),         dim3(64),  0, stream, neg, lens, dirs, idx_map);
    hipLaunchKernelGGL(k_scatter, dim3(64),        dim3(256), 0, stream, lens, idx_map, out);
    hipLaunchKernelGGL(k_gather,  dim3(3072),      dim3(256), 0, stream, z_p, m_p, logs_p, logs_q,
                       lens, idx_map, out, partials);
    hipLaunchKernelGGL(k_final,   dim3(1),         dim3(256), 0, stream, partials, lens, out);
}